// Round 3
// baseline (22036.076 us; speedup 1.0000x reference)
//
#include <hip/hip_runtime.h>
#include <stdint.h>

// LSTM forward T=512, B=64, H=800 — persistent cooperative kernel.
// bf16x3 split-precision MFMA (acc += Ahi*Bhi + Ahi*Blo + Alo*Bhi).
//
// ws layout (bytes):
//   [0,       204800)  c state        (64*800 f32)
//   [204800,  409600)  h_hi[2]        (2 x 64*800 bf16) double-buffered
//   [409600,  614400)  h_lo[2]
//   [614400,  614656)  barrier counter
//   [614656,  627456)  biasbuf        (100*32 f32)
//   [627456, 21107456) wbuf           100u x 50kt x {hi,lo} 32x32 bf16 tiles

#define T_STEPS 512
#define B_SZ    64
#define H_SZ    800
#define KT_X    25
#define KT_TOT  50
#define NU      100
#define NBLK    200

#define OFF_C    0
#define OFF_HHI  204800
#define OFF_HLO  409600
#define OFF_CTR  614400
#define OFF_BIAS 614656
#define OFF_WBUF 627456

typedef short bf16x8 __attribute__((ext_vector_type(8)));
typedef float f32x4  __attribute__((ext_vector_type(4)));

__device__ __forceinline__ unsigned short f2bf_rne(float f) {
    unsigned int u = __float_as_uint(f);
    unsigned int r = u + 0x7FFFu + ((u >> 16) & 1u);
    return (unsigned short)(r >> 16);
}
__device__ __forceinline__ float bf2f(unsigned short h) {
    return __uint_as_float(((unsigned int)h) << 16);
}
__device__ __forceinline__ float sigmoid_fast(float v) {
    return 1.f / (1.f + __expf(-v));
}
__device__ __forceinline__ float tanh_fast(float v) {
    v = fminf(fmaxf(v, -15.f), 15.f);   // exp overflow guard (c can reach ~±500)
    float e = __expf(2.f * v);
    return (e - 1.f) / (e + 1.f);
}

// ---------------------------------------------------------------------------
// One-time prep: W_ih/W_hh -> per-(u,kt) 32x32 bf16 hi/lo MFMA fragment tiles.
// ---------------------------------------------------------------------------
__global__ __launch_bounds__(256) void lstm_prep(
        const float* __restrict__ Wih, const float* __restrict__ Whh,
        const float* __restrict__ bih, const float* __restrict__ bhh,
        unsigned short* __restrict__ wbuf, float* __restrict__ biasbuf) {
    int bid = blockIdx.x;
    int u = bid / KT_TOT, kt = bid % KT_TOT;
    int tid = threadIdx.x;
    int vrow = tid >> 3;            // 0..31 (gate*8 + unit)
    int kk0  = (tid & 7) * 4;
    int g = vrow >> 3, jj = vrow & 7;
    size_t srow = (size_t)g * H_SZ + u * 8 + jj;
    const float* src = (kt < KT_X)
        ? (Wih + srow * H_SZ + kt * 32 + kk0)
        : (Whh + srow * H_SZ + (kt - KT_X) * 32 + kk0);
    float4 v = *(const float4*)src;
    float f[4] = {v.x, v.y, v.z, v.w};
    unsigned short hi[4], lo[4];
#pragma unroll
    for (int i = 0; i < 4; ++i) {
        hi[i] = f2bf_rne(f[i]);
        lo[i] = f2bf_rne(f[i] - bf2f(hi[i]));
    }
    size_t tbase = ((size_t)u * KT_TOT + kt) * 2048;
    unsigned short* dhi = wbuf + tbase + vrow * 32 + kk0;
    unsigned short* dlo = dhi + 1024;
    *(ushort4*)dhi = make_ushort4(hi[0], hi[1], hi[2], hi[3]);
    *(ushort4*)dlo = make_ushort4(lo[0], lo[1], lo[2], lo[3]);

    if (kt == 0 && tid < 32) {
        int vv = tid;
        size_t r = (size_t)(vv >> 3) * H_SZ + u * 8 + (vv & 7);
        biasbuf[u * 32 + vv] = bih[r] + bhh[r];
    }
}

// ---------------------------------------------------------------------------
// Persistent kernel: 200 blocks (u, mhalf) x 512 threads (8 waves).
// Wave w: nt=w&1, mt=(w>>1)&1, kh=w>>2 (K-split halves). One grid barrier/step.
// ---------------------------------------------------------------------------
__global__ __launch_bounds__(512, 2) void lstm_persist(
        const float* __restrict__ x,
        const unsigned short* __restrict__ wbuf,
        const float* __restrict__ biasbuf,
        unsigned short* __restrict__ hhi,   // [2][64][800]
        unsigned short* __restrict__ hlo,
        float* __restrict__ cbuf,
        float* __restrict__ out,
        unsigned int* __restrict__ ctr) {
    extern __shared__ unsigned short whh[];   // 25 kt * 2048 shorts = 102400 B
    __shared__ float gl[2][32][33];

    int bid = blockIdx.x;
    int u = bid >> 1, mhalf = bid & 1;
    int tid = threadIdx.x;
    int lane = tid & 63;
    int w = tid >> 6;
    int nt = w & 1, mt = (w >> 1) & 1, kh = w >> 2;
    int rlane = lane & 15, ksel = lane >> 4, kgrp = ksel * 8;
    int brow = mhalf * 32 + mt * 16 + rlane;
    int kt0 = kh ? 13 : 0, kt1 = kh ? 25 : 13;

    // ---- stage this u's W_hh tiles (kt 25..49) into LDS, linear layout ----
    {
        const uint4* src = (const uint4*)(wbuf + ((size_t)u * KT_TOT + KT_X) * 2048);
        uint4* dst = (uint4*)whh;
        for (int g = tid; g < 6400; g += 512) dst[g] = src[g];
    }
    __syncthreads();

    const unsigned short* wih_tile =
        wbuf + (size_t)u * KT_TOT * 2048 + (nt * 16 + rlane) * 32 + kgrp;
    const unsigned short* whh_tile = whh + (nt * 16 + rlane) * 32 + kgrp;

    // epilogue constants (tid<256 handles the 32x8 output cells)
    int bl = tid >> 3, jl = tid & 7;
    int b  = mhalf * 32 + bl;
    int ju = u * 8 + jl;
    size_t sidx = (size_t)b * H_SZ + ju;
    float b_i = 0.f, b_f = 0.f, b_g = 0.f, b_o = 0.f;
    if (tid < 256) {
        b_i = biasbuf[u * 32 + jl];
        b_f = biasbuf[u * 32 + 8 + jl];
        b_g = biasbuf[u * 32 + 16 + jl];
        b_o = biasbuf[u * 32 + 24 + jl];
    }

    for (int t = 0; t < T_STEPS; ++t) {
        // ---- x phase (independent of h_{t-1}; runs before the barrier) ----
        f32x4 acc = {0.f, 0.f, 0.f, 0.f};
        const float* xrow = x + ((size_t)t * B_SZ + brow) * H_SZ + kgrp;
#pragma unroll 4
        for (int kt = kt0; kt < kt1; ++kt) {
            const float* xp = xrow + kt * 32;
            float4 v0 = *(const float4*)xp;
            float4 v1 = *(const float4*)(xp + 4);
            float f[8] = {v0.x, v0.y, v0.z, v0.w, v1.x, v1.y, v1.z, v1.w};
            bf16x8 ahi, alo;
#pragma unroll
            for (int j = 0; j < 8; ++j) {
                unsigned int ub = __float_as_uint(f[j]);
                ahi[j] = (short)(ub >> 16);                       // trunc hi
                float lof = f[j] - __uint_as_float(ub & 0xffff0000u);
                alo[j] = (short)f2bf_rne(lof);                    // RNE lo
            }
            bf16x8 bhi = *(const bf16x8*)(wih_tile + (size_t)kt * 2048);
            bf16x8 blo = *(const bf16x8*)(wih_tile + (size_t)kt * 2048 + 1024);
            acc = __builtin_amdgcn_mfma_f32_16x16x32_bf16(ahi, bhi, acc, 0, 0, 0);
            acc = __builtin_amdgcn_mfma_f32_16x16x32_bf16(ahi, blo, acc, 0, 0, 0);
            acc = __builtin_amdgcn_mfma_f32_16x16x32_bf16(alo, bhi, acc, 0, 0, 0);
        }

        // ---- grid barrier: publish h_{t-1}/epilogue(t-1), await all blocks ----
        __threadfence();
        __syncthreads();
        if (tid == 0) {
            atomicAdd(ctr, 1u);
            unsigned target = (unsigned)NBLK * (unsigned)(t + 1);
            while (__hip_atomic_load(ctr, __ATOMIC_RELAXED, __HIP_MEMORY_SCOPE_AGENT) < target)
                __builtin_amdgcn_s_sleep(2);
            __threadfence();
        }
        __syncthreads();

        // ---- h phase: A from h_{t-1} (L2), B from LDS ----
        {
            int pprev = (t + 1) & 1;                 // h_{t-1} buffer
            const unsigned short* hh = hhi + pprev * 51200 + (size_t)brow * H_SZ;
            const unsigned short* hl = hlo + pprev * 51200 + (size_t)brow * H_SZ;
#pragma unroll 4
            for (int lkt = kt0; lkt < kt1; ++lkt) {
                int k = lkt * 32 + kgrp;
                bf16x8 ahi = *(const bf16x8*)(hh + k);
                bf16x8 alo = *(const bf16x8*)(hl + k);
                bf16x8 bhi = *(const bf16x8*)(whh_tile + lkt * 2048);
                bf16x8 blo = *(const bf16x8*)(whh_tile + lkt * 2048 + 1024);
                acc = __builtin_amdgcn_mfma_f32_16x16x32_bf16(ahi, bhi, acc, 0, 0, 0);
                acc = __builtin_amdgcn_mfma_f32_16x16x32_bf16(ahi, blo, acc, 0, 0, 0);
                acc = __builtin_amdgcn_mfma_f32_16x16x32_bf16(alo, bhi, acc, 0, 0, 0);
            }
        }

        // ---- epilogue: cross-wave gate exchange, activations, c/h update ----
#pragma unroll
        for (int j = 0; j < 4; ++j)
            gl[kh][mt * 16 + ksel * 4 + j][nt * 16 + rlane] = acc[j];
        __syncthreads();
        if (tid < 256) {
            float gi = gl[0][bl][jl]      + gl[1][bl][jl]      + b_i;
            float gf = gl[0][bl][8 + jl]  + gl[1][bl][8 + jl]  + b_f;
            float gg = gl[0][bl][16 + jl] + gl[1][bl][16 + jl] + b_g;
            float go = gl[0][bl][24 + jl] + gl[1][bl][24 + jl] + b_o;
            float cold = cbuf[sidx];
            float ig = sigmoid_fast(gi);
            float fg = sigmoid_fast(gf);
            float gt = tanh_fast(gg);
            float og = sigmoid_fast(go);
            float cn = fg * cold + ig * gt;
            float hn = og * tanh_fast(cn);
            cbuf[sidx] = cn;
            out[((size_t)t * B_SZ + b) * H_SZ + ju] = hn;
            int pcur = t & 1;
            unsigned short h16 = f2bf_rne(hn);
            hhi[pcur * 51200 + sidx] = h16;
            hlo[pcur * 51200 + sidx] = f2bf_rne(hn - bf2f(h16));
        }
        // gl reuse at t+1 is fenced by the next iteration's barrier syncthreads
    }
}

// ---------------------------------------------------------------------------
extern "C" void kernel_launch(void* const* d_in, const int* in_sizes, int n_in,
                              void* d_out, int out_size, void* d_ws, size_t ws_size,
                              hipStream_t stream) {
    const float* x   = (const float*)d_in[0];
    const float* Wih = (const float*)d_in[1];
    const float* Whh = (const float*)d_in[2];
    const float* bih = (const float*)d_in[3];
    const float* bhh = (const float*)d_in[4];
    float* out = (float*)d_out;

    char* ws = (char*)d_ws;
    float* cbuf          = (float*)(ws + OFF_C);
    unsigned short* hhi  = (unsigned short*)(ws + OFF_HHI);
    unsigned short* hlo  = (unsigned short*)(ws + OFF_HLO);
    unsigned int* ctr    = (unsigned int*)(ws + OFF_CTR);
    float* biasbuf       = (float*)(ws + OFF_BIAS);
    unsigned short* wbuf = (unsigned short*)(ws + OFF_WBUF);

    // zero c, h[2] (hi/lo), barrier counter (ws is re-poisoned before each call)
    hipMemsetAsync(ws, 0, OFF_BIAS, stream);

    lstm_prep<<<NU * KT_TOT, 256, 0, stream>>>(Wih, Whh, bih, bhh, wbuf, biasbuf);

    hipFuncSetAttribute((const void*)lstm_persist,
                        hipFuncAttributeMaxDynamicSharedMemorySize, 102400);
    void* args[] = {(void*)&x, (void*)&wbuf, (void*)&biasbuf, (void*)&hhi,
                    (void*)&hlo, (void*)&cbuf, (void*)&out, (void*)&ctr};
    hipLaunchCooperativeKernel((const void*)lstm_persist, dim3(NBLK), dim3(512),
                               args, 102400, stream);
}

// Round 6
// 8471.117 us; speedup vs baseline: 2.6013x; 2.6013x over previous
//
#include <hip/hip_runtime.h>
#include <stdint.h>

// LSTM forward T=512, B=64, H=800 — persistent cooperative kernel, fence-free.
// bf16x3 split-precision MFMA (acc += Ahi*Bhi + Ahi*Blo + Alo*Bhi).
//
// Cross-block h flow uses agent-scope relaxed atomics (coherence point), so NO
// __threadfence is needed => no per-step L2 invalidate => W stays L2-resident.
//
// ws layout (bytes):
//   [0,       204800)  c state        (64*800 f32)
//   [204800,  409600)  h_hi[2]        (2 x 64*800 bf16) double-buffered
//   [409600,  614400)  h_lo[2]
//   [614400,  614656)  barrier counter
//   [614656,  627456)  biasbuf        (100*32 f32)
//   [627456, 21107456) wbuf           100u x 50kt x {hi,lo} 32x32 bf16 tiles
//   [21107456, 73536256)  xhi  (512*64*800 bf16)   } only if ws_size allows
//   [73536256, 125965056) xlo  (512*64*800 bf16)   }

#define T_STEPS 512
#define B_SZ    64
#define H_SZ    800
#define KT_X    25
#define KT_TOT  50
#define NU      100
#define NBLK    200

#define OFF_C    0
#define OFF_HHI  204800
#define OFF_HLO  409600
#define OFF_CTR  614400
#define OFF_BIAS 614656
#define OFF_WBUF 627456
#define OFF_XHI  21107456
#define OFF_XLO  73536256
#define WS_NEED_PRE 125965056ULL

typedef short bf16x8 __attribute__((ext_vector_type(8)));
typedef float f32x4  __attribute__((ext_vector_type(4)));

__device__ __forceinline__ unsigned short f2bf_rne(float f) {
    unsigned int u = __float_as_uint(f);
    unsigned int r = u + 0x7FFFu + ((u >> 16) & 1u);
    return (unsigned short)(r >> 16);
}
__device__ __forceinline__ float bf2f(unsigned short h) {
    return __uint_as_float(((unsigned int)h) << 16);
}
__device__ __forceinline__ float sigmoid_fast(float v) {
    return 1.f / (1.f + __expf(-v));
}
__device__ __forceinline__ float tanh_fast(float v) {
    v = fminf(fmaxf(v, -15.f), 15.f);
    float e = __expf(2.f * v);
    return (e - 1.f) / (e + 1.f);
}
// trunc-split: hi = trunc-bf16(f), lo = trunc-bf16(f - hi). ~17-bit total.
__device__ __forceinline__ void split2(float f, unsigned short& hi, unsigned short& lo) {
    unsigned int ub = __float_as_uint(f);
    hi = (unsigned short)(ub >> 16);
    float lof = f - __uint_as_float(ub & 0xffff0000u);
    lo = (unsigned short)(__float_as_uint(lof) >> 16);
}
// coherent 16B fragment load from agent-scope shared state
__device__ __forceinline__ bf16x8 ald16(const unsigned short* p) {
    union { unsigned long long q[2]; bf16x8 v; } U;
    U.q[0] = __hip_atomic_load((const unsigned long long*)p,
                               __ATOMIC_RELAXED, __HIP_MEMORY_SCOPE_AGENT);
    U.q[1] = __hip_atomic_load((const unsigned long long*)(p + 4),
                               __ATOMIC_RELAXED, __HIP_MEMORY_SCOPE_AGENT);
    return U.v;
}

// ---------------------------------------------------------------------------
// One-time prep: W_ih/W_hh -> per-(u,kt) 32x32 bf16 hi/lo MFMA fragment tiles.
// ---------------------------------------------------------------------------
__global__ __launch_bounds__(256) void lstm_prep(
        const float* __restrict__ Wih, const float* __restrict__ Whh,
        const float* __restrict__ bih, const float* __restrict__ bhh,
        unsigned short* __restrict__ wbuf, float* __restrict__ biasbuf) {
    int bid = blockIdx.x;
    int u = bid / KT_TOT, kt = bid % KT_TOT;
    int tid = threadIdx.x;
    int vrow = tid >> 3;
    int kk0  = (tid & 7) * 4;
    int g = vrow >> 3, jj = vrow & 7;
    size_t srow = (size_t)g * H_SZ + u * 8 + jj;
    const float* src = (kt < KT_X)
        ? (Wih + srow * H_SZ + kt * 32 + kk0)
        : (Whh + srow * H_SZ + (kt - KT_X) * 32 + kk0);
    float4 v = *(const float4*)src;
    float f[4] = {v.x, v.y, v.z, v.w};
    unsigned short hi[4], lo[4];
#pragma unroll
    for (int i = 0; i < 4; ++i) {
        hi[i] = f2bf_rne(f[i]);
        lo[i] = f2bf_rne(f[i] - bf2f(hi[i]));
    }
    size_t tbase = ((size_t)u * KT_TOT + kt) * 2048;
    unsigned short* dhi = wbuf + tbase + vrow * 32 + kk0;
    unsigned short* dlo = dhi + 1024;
    *(ushort4*)dhi = make_ushort4(hi[0], hi[1], hi[2], hi[3]);
    *(ushort4*)dlo = make_ushort4(lo[0], lo[1], lo[2], lo[3]);

    if (kt == 0 && tid < 32) {
        int vv = tid;
        size_t r = (size_t)(vv >> 3) * H_SZ + u * 8 + (vv & 7);
        biasbuf[u * 32 + vv] = bih[r] + bhh[r];
    }
}

// ---------------------------------------------------------------------------
// One-time x split: x f32 -> xhi/xlo bf16. 6,553,600 float4s exactly.
// ---------------------------------------------------------------------------
__global__ __launch_bounds__(256) void lstm_xsplit(
        const float* __restrict__ x, unsigned short* __restrict__ xhi,
        unsigned short* __restrict__ xlo) {
    size_t i = (size_t)blockIdx.x * 256 + threadIdx.x;
    float4 v = ((const float4*)x)[i];
    ushort4 h, l;
    split2(v.x, h.x, l.x); split2(v.y, h.y, l.y);
    split2(v.z, h.z, l.z); split2(v.w, h.w, l.w);
    ((ushort4*)xhi)[i] = h;
    ((ushort4*)xlo)[i] = l;
}

// ---------------------------------------------------------------------------
// Phase helpers: batched load -> dual-chain MFMA. NKT is compile-time.
// ---------------------------------------------------------------------------
template<int NKT>
__device__ __forceinline__ f32x4 xphase_pre(const unsigned short* xh,
                                            const unsigned short* xl,
                                            const unsigned short* wt) {
    bf16x8 ah[NKT], al[NKT], bh[NKT], bl[NKT];
#pragma unroll
    for (int i = 0; i < NKT; ++i) {
        ah[i] = *(const bf16x8*)(xh + i * 32);
        al[i] = *(const bf16x8*)(xl + i * 32);
    }
#pragma unroll
    for (int i = 0; i < NKT; ++i) {
        bh[i] = *(const bf16x8*)(wt + (size_t)i * 2048);
        bl[i] = *(const bf16x8*)(wt + (size_t)i * 2048 + 1024);
    }
    f32x4 a0 = {0.f, 0.f, 0.f, 0.f}, a1 = {0.f, 0.f, 0.f, 0.f};
#pragma unroll
    for (int i = 0; i < NKT; ++i) {
        f32x4& a = (i & 1) ? a1 : a0;
        a = __builtin_amdgcn_mfma_f32_16x16x32_bf16(ah[i], bh[i], a, 0, 0, 0);
        a = __builtin_amdgcn_mfma_f32_16x16x32_bf16(ah[i], bl[i], a, 0, 0, 0);
        a = __builtin_amdgcn_mfma_f32_16x16x32_bf16(al[i], bh[i], a, 0, 0, 0);
    }
    return a0 + a1;
}

template<int NKT>
__device__ __forceinline__ f32x4 xphase_cvt(const float* xp,
                                            const unsigned short* wt) {
    float4 xr[2 * NKT];
#pragma unroll
    for (int i = 0; i < NKT; ++i) {
        xr[2 * i]     = *(const float4*)(xp + i * 32);
        xr[2 * i + 1] = *(const float4*)(xp + i * 32 + 4);
    }
    bf16x8 bh[NKT], bl[NKT];
#pragma unroll
    for (int i = 0; i < NKT; ++i) {
        bh[i] = *(const bf16x8*)(wt + (size_t)i * 2048);
        bl[i] = *(const bf16x8*)(wt + (size_t)i * 2048 + 1024);
    }
    f32x4 a0 = {0.f, 0.f, 0.f, 0.f}, a1 = {0.f, 0.f, 0.f, 0.f};
#pragma unroll
    for (int i = 0; i < NKT; ++i) {
        float f[8] = {xr[2*i].x, xr[2*i].y, xr[2*i].z, xr[2*i].w,
                      xr[2*i+1].x, xr[2*i+1].y, xr[2*i+1].z, xr[2*i+1].w};
        bf16x8 ah, al;
#pragma unroll
        for (int j = 0; j < 8; ++j) {
            unsigned short h16, l16;
            split2(f[j], h16, l16);
            ah[j] = (short)h16; al[j] = (short)l16;
        }
        f32x4& a = (i & 1) ? a1 : a0;
        a = __builtin_amdgcn_mfma_f32_16x16x32_bf16(ah, bh[i], a, 0, 0, 0);
        a = __builtin_amdgcn_mfma_f32_16x16x32_bf16(ah, bl[i], a, 0, 0, 0);
        a = __builtin_amdgcn_mfma_f32_16x16x32_bf16(al, bh[i], a, 0, 0, 0);
    }
    return a0 + a1;
}

template<int NKT>
__device__ __forceinline__ f32x4 hphase(const unsigned short* hh,
                                        const unsigned short* hl,
                                        const unsigned short* wlds, f32x4 acc) {
    bf16x8 ah[NKT], al[NKT], bh[NKT], bl[NKT];
#pragma unroll
    for (int i = 0; i < NKT; ++i) {
        ah[i] = ald16(hh + i * 32);
        al[i] = ald16(hl + i * 32);
    }
#pragma unroll
    for (int i = 0; i < NKT; ++i) {
        bh[i] = *(const bf16x8*)(wlds + (size_t)i * 2048);
        bl[i] = *(const bf16x8*)(wlds + (size_t)i * 2048 + 1024);
    }
    f32x4 a0 = acc, a1 = {0.f, 0.f, 0.f, 0.f};
#pragma unroll
    for (int i = 0; i < NKT; ++i) {
        f32x4& a = (i & 1) ? a1 : a0;
        a = __builtin_amdgcn_mfma_f32_16x16x32_bf16(ah[i], bh[i], a, 0, 0, 0);
        a = __builtin_amdgcn_mfma_f32_16x16x32_bf16(ah[i], bl[i], a, 0, 0, 0);
        a = __builtin_amdgcn_mfma_f32_16x16x32_bf16(al[i], bh[i], a, 0, 0, 0);
    }
    return a0 + a1;
}

// ---------------------------------------------------------------------------
// Persistent kernel: 200 blocks (u, mhalf) x 512 threads (8 waves).
// Wave w: nt=w&1, mt=(w>>1)&1, kh=w>>2 (K halves 13/12 kt). One barrier/step.
// ---------------------------------------------------------------------------
__global__ __launch_bounds__(512, 2) void lstm_persist(
        const float* __restrict__ x,
        const unsigned short* __restrict__ wbuf,
        const float* __restrict__ biasbuf,
        unsigned short* __restrict__ hhi,   // [2][64][800]
        unsigned short* __restrict__ hlo,
        float* __restrict__ cbuf,
        float* __restrict__ out,
        unsigned int* __restrict__ ctr,
        const unsigned short* __restrict__ xhi,
        const unsigned short* __restrict__ xlo,
        int use_pre) {
    extern __shared__ unsigned short whh[];   // 25 kt * 2048 shorts = 102400 B
    __shared__ float gl[2][32][33];

    int bid = blockIdx.x;
    int u = bid >> 1, mhalf = bid & 1;
    int tid = threadIdx.x;
    int lane = tid & 63;
    int w = tid >> 6;
    int nt = w & 1, mt = (w >> 1) & 1, kh = w >> 2;
    int rlane = lane & 15, ksel = lane >> 4, kgrp = ksel * 8;
    int brow = mhalf * 32 + mt * 16 + rlane;

    // ---- stage this u's W_hh tiles (kt 25..49) into LDS ----
    {
        const uint4* src = (const uint4*)(wbuf + ((size_t)u * KT_TOT + KT_X) * 2048);
        uint4* dst = (uint4*)whh;
        for (int g = tid; g < 6400; g += 512) dst[g] = src[g];
    }
    __syncthreads();

    const unsigned short* wih_tile =
        wbuf + (size_t)u * KT_TOT * 2048 + (nt * 16 + rlane) * 32 + kgrp;
    const unsigned short* whh_tile = whh + (nt * 16 + rlane) * 32 + kgrp;

    // epilogue constants (tid<256 -> 32 batch-rows x 8 units)
    int bl_ = tid >> 3, jl = tid & 7;
    int b  = mhalf * 32 + bl_;
    int ju = u * 8 + jl;
    size_t sidx = (size_t)b * H_SZ + ju;
    float b_i = 0.f, b_f = 0.f, b_g = 0.f, b_o = 0.f;
    if (tid < 256) {
        b_i = biasbuf[u * 32 + jl];
        b_f = biasbuf[u * 32 + 8 + jl];
        b_g = biasbuf[u * 32 + 16 + jl];
        b_o = biasbuf[u * 32 + 24 + jl];
    }

    for (int t = 0; t < T_STEPS; ++t) {
        // ---- x phase (independent of h_{t-1}; before the barrier) ----
        f32x4 xacc;
        if (use_pre) {
            const unsigned short* xh = xhi + ((size_t)t * B_SZ + brow) * H_SZ + kgrp;
            const unsigned short* xl = xlo + ((size_t)t * B_SZ + brow) * H_SZ + kgrp;
            xacc = (kh == 0) ? xphase_pre<13>(xh, xl, wih_tile)
                             : xphase_pre<12>(xh + 13 * 32, xl + 13 * 32,
                                              wih_tile + 13 * 2048);
        } else {
            const float* xrow = x + ((size_t)t * B_SZ + brow) * H_SZ + kgrp;
            xacc = (kh == 0) ? xphase_cvt<13>(xrow, wih_tile)
                             : xphase_cvt<12>(xrow + 13 * 32, wih_tile + 13 * 2048);
        }

        // ---- barrier: syncthreads drains all waves' h-stores (vmcnt(0)),
        //      then monotonic counter. NO threadfence (h flows via atomics). ----
        __syncthreads();
        if (tid == 0) {
            atomicAdd(ctr, 1u);
            unsigned target = (unsigned)NBLK * (unsigned)(t + 1);
            while (__hip_atomic_load(ctr, __ATOMIC_RELAXED,
                                     __HIP_MEMORY_SCOPE_AGENT) < target)
                __builtin_amdgcn_s_sleep(1);
        }
        __syncthreads();

        // ---- h phase: A = h_{t-1} via coherent atomic loads, B from LDS ----
        {
            int pprev = (t + 1) & 1;
            const unsigned short* hh =
                hhi + (size_t)pprev * 51200 + (size_t)brow * H_SZ + kgrp;
            const unsigned short* hl =
                hlo + (size_t)pprev * 51200 + (size_t)brow * H_SZ + kgrp;
            xacc = (kh == 0)
                ? hphase<13>(hh, hl, whh_tile, xacc)
                : hphase<12>(hh + 13 * 32, hl + 13 * 32,
                             whh_tile + 13 * 2048, xacc);
        }

        // ---- epilogue ----
#pragma unroll
        for (int j = 0; j < 4; ++j)
            gl[kh][mt * 16 + ksel * 4 + j][nt * 16 + rlane] = xacc[j];
        __syncthreads();
        if (tid < 256) {
            float gi = gl[0][bl_][jl]      + gl[1][bl_][jl]      + b_i;
            float gf = gl[0][bl_][8 + jl]  + gl[1][bl_][8 + jl]  + b_f;
            float gg = gl[0][bl_][16 + jl] + gl[1][bl_][16 + jl] + b_g;
            float go = gl[0][bl_][24 + jl] + gl[1][bl_][24 + jl] + b_o;
            float cold = cbuf[sidx];
            float ig = sigmoid_fast(gi);
            float fg = sigmoid_fast(gf);
            float gt = tanh_fast(gg);
            float og = sigmoid_fast(go);
            float cn = fg * cold + ig * gt;
            float hn = og * tanh_fast(cn);
            cbuf[sidx] = cn;
            __builtin_nontemporal_store(hn, out + ((size_t)t * B_SZ + b) * H_SZ + ju);
            unsigned short h16, l16;
            split2(hn, h16, l16);
            size_t pcur = (size_t)(t & 1) * 51200;
            __hip_atomic_store(hhi + pcur + sidx, h16,
                               __ATOMIC_RELAXED, __HIP_MEMORY_SCOPE_AGENT);
            __hip_atomic_store(hlo + pcur + sidx, l16,
                               __ATOMIC_RELAXED, __HIP_MEMORY_SCOPE_AGENT);
        }
        // next iteration's arrival __syncthreads drains these stores before
        // the counter increment; readers use coherent atomic loads.
    }
}

// ---------------------------------------------------------------------------
extern "C" void kernel_launch(void* const* d_in, const int* in_sizes, int n_in,
                              void* d_out, int out_size, void* d_ws, size_t ws_size,
                              hipStream_t stream) {
    const float* x   = (const float*)d_in[0];
    const float* Wih = (const float*)d_in[1];
    const float* Whh = (const float*)d_in[2];
    const float* bih = (const float*)d_in[3];
    const float* bhh = (const float*)d_in[4];
    float* out = (float*)d_out;

    char* ws = (char*)d_ws;
    float* cbuf          = (float*)(ws + OFF_C);
    unsigned short* hhi  = (unsigned short*)(ws + OFF_HHI);
    unsigned short* hlo  = (unsigned short*)(ws + OFF_HLO);
    unsigned int* ctr    = (unsigned int*)(ws + OFF_CTR);
    float* biasbuf       = (float*)(ws + OFF_BIAS);
    unsigned short* wbuf = (unsigned short*)(ws + OFF_WBUF);
    unsigned short* xhi  = (unsigned short*)(ws + OFF_XHI);
    unsigned short* xlo  = (unsigned short*)(ws + OFF_XLO);
    int use_pre = (ws_size >= WS_NEED_PRE) ? 1 : 0;

    hipMemsetAsync(ws, 0, OFF_BIAS, stream);

    lstm_prep<<<NU * KT_TOT, 256, 0, stream>>>(Wih, Whh, bih, bhh, wbuf, biasbuf);
    if (use_pre)
        lstm_xsplit<<<25600, 256, 0, stream>>>(x, xhi, xlo);

    hipFuncSetAttribute((const void*)lstm_persist,
                        hipFuncAttributeMaxDynamicSharedMemorySize, 102400);
    void* args[] = {(void*)&x, (void*)&wbuf, (void*)&biasbuf, (void*)&hhi,
                    (void*)&hlo, (void*)&cbuf, (void*)&out, (void*)&ctr,
                    (void*)&xhi, (void*)&xlo, (void*)&use_pre};
    hipLaunchCooperativeKernel((const void*)lstm_persist, dim3(NBLK), dim3(512),
                               args, 102400, stream);
}

// Round 7
// 7160.284 us; speedup vs baseline: 3.0775x; 1.1831x over previous
//
#include <hip/hip_runtime.h>
#include <stdint.h>

// LSTM forward T=512, B=64, H=800 — persistent cooperative kernel.
// Round 7: flag-array barrier (parallel arrive/poll, no serialized atomicAdd)
//          + xphase(t+1) overlapped with barrier wait.
// bf16x3 split-precision MFMA (acc += Ahi*Bhi + Ahi*Blo + Alo*Bhi).
//
// ws layout (bytes):
//   [0,       204800)  c state        (64*800 f32)
//   [204800,  409600)  h_hi[2]        (2 x 64*800 bf16) double-buffered
//   [409600,  614400)  h_lo[2]
//   [614400,  615424)  flags          (200 u32 + pad)
//   [615424,  628224)  biasbuf        (100*32 f32)
//   [628224, 21108224) wbuf           100u x 50kt x {hi,lo} 32x32 bf16 tiles
//   [21108224, 73537024)  xhi  (512*64*800 bf16)  } only if ws_size allows
//   [73537024, 125965824) xlo                     }

#define T_STEPS 512
#define B_SZ    64
#define H_SZ    800
#define KT_X    25
#define KT_TOT  50
#define NU      100
#define NBLK    200

#define OFF_C     0
#define OFF_HHI   204800
#define OFF_HLO   409600
#define OFF_FLAGS 614400
#define OFF_BIAS  615424
#define OFF_WBUF  628224
#define OFF_XHI   21108224ULL
#define OFF_XLO   73537024ULL
#define WS_NEED_PRE 125965824ULL

typedef short bf16x8 __attribute__((ext_vector_type(8)));
typedef float f32x4  __attribute__((ext_vector_type(4)));

__device__ __forceinline__ unsigned short f2bf_rne(float f) {
    unsigned int u = __float_as_uint(f);
    unsigned int r = u + 0x7FFFu + ((u >> 16) & 1u);
    return (unsigned short)(r >> 16);
}
__device__ __forceinline__ float bf2f(unsigned short h) {
    return __uint_as_float(((unsigned int)h) << 16);
}
__device__ __forceinline__ float sigmoid_fast(float v) {
    return 1.f / (1.f + __expf(-v));
}
__device__ __forceinline__ float tanh_fast(float v) {
    v = fminf(fmaxf(v, -15.f), 15.f);
    float e = __expf(2.f * v);
    return (e - 1.f) / (e + 1.f);
}
// trunc-split: hi = trunc-bf16(f), lo = trunc-bf16(f - hi). ~17-bit total.
__device__ __forceinline__ void split2(float f, unsigned short& hi, unsigned short& lo) {
    unsigned int ub = __float_as_uint(f);
    hi = (unsigned short)(ub >> 16);
    float lof = f - __uint_as_float(ub & 0xffff0000u);
    lo = (unsigned short)(__float_as_uint(lof) >> 16);
}
// coherent 16B fragment load from agent-scope shared state
__device__ __forceinline__ bf16x8 ald16(const unsigned short* p) {
    union { unsigned long long q[2]; bf16x8 v; } U;
    U.q[0] = __hip_atomic_load((const unsigned long long*)p,
                               __ATOMIC_RELAXED, __HIP_MEMORY_SCOPE_AGENT);
    U.q[1] = __hip_atomic_load((const unsigned long long*)(p + 4),
                               __ATOMIC_RELAXED, __HIP_MEMORY_SCOPE_AGENT);
    return U.v;
}

// ---------------------------------------------------------------------------
// One-time prep: W_ih/W_hh -> per-(u,kt) 32x32 bf16 hi/lo MFMA fragment tiles.
// ---------------------------------------------------------------------------
__global__ __launch_bounds__(256) void lstm_prep(
        const float* __restrict__ Wih, const float* __restrict__ Whh,
        const float* __restrict__ bih, const float* __restrict__ bhh,
        unsigned short* __restrict__ wbuf, float* __restrict__ biasbuf) {
    int bid = blockIdx.x;
    int u = bid / KT_TOT, kt = bid % KT_TOT;
    int tid = threadIdx.x;
    int vrow = tid >> 3;
    int kk0  = (tid & 7) * 4;
    int g = vrow >> 3, jj = vrow & 7;
    size_t srow = (size_t)g * H_SZ + u * 8 + jj;
    const float* src = (kt < KT_X)
        ? (Wih + srow * H_SZ + kt * 32 + kk0)
        : (Whh + srow * H_SZ + (kt - KT_X) * 32 + kk0);
    float4 v = *(const float4*)src;
    float f[4] = {v.x, v.y, v.z, v.w};
    unsigned short hi[4], lo[4];
#pragma unroll
    for (int i = 0; i < 4; ++i) {
        hi[i] = f2bf_rne(f[i]);
        lo[i] = f2bf_rne(f[i] - bf2f(hi[i]));
    }
    size_t tbase = ((size_t)u * KT_TOT + kt) * 2048;
    unsigned short* dhi = wbuf + tbase + vrow * 32 + kk0;
    unsigned short* dlo = dhi + 1024;
    *(ushort4*)dhi = make_ushort4(hi[0], hi[1], hi[2], hi[3]);
    *(ushort4*)dlo = make_ushort4(lo[0], lo[1], lo[2], lo[3]);

    if (kt == 0 && tid < 32) {
        int vv = tid;
        size_t r = (size_t)(vv >> 3) * H_SZ + u * 8 + (vv & 7);
        biasbuf[u * 32 + vv] = bih[r] + bhh[r];
    }
}

// ---------------------------------------------------------------------------
// One-time x split: x f32 -> xhi/xlo bf16. 6,553,600 float4s exactly.
// ---------------------------------------------------------------------------
__global__ __launch_bounds__(256) void lstm_xsplit(
        const float* __restrict__ x, unsigned short* __restrict__ xhi,
        unsigned short* __restrict__ xlo) {
    size_t i = (size_t)blockIdx.x * 256 + threadIdx.x;
    float4 v = ((const float4*)x)[i];
    ushort4 h, l;
    split2(v.x, h.x, l.x); split2(v.y, h.y, l.y);
    split2(v.z, h.z, l.z); split2(v.w, h.w, l.w);
    ((ushort4*)xhi)[i] = h;
    ((ushort4*)xlo)[i] = l;
}

// ---------------------------------------------------------------------------
// Phase helpers: batched load -> dual-chain MFMA. NKT is compile-time.
// ---------------------------------------------------------------------------
template<int NKT>
__device__ __forceinline__ f32x4 xphase_pre(const unsigned short* xh,
                                            const unsigned short* xl,
                                            const unsigned short* wt) {
    bf16x8 ah[NKT], al[NKT], bh[NKT], bl[NKT];
#pragma unroll
    for (int i = 0; i < NKT; ++i) {
        ah[i] = *(const bf16x8*)(xh + i * 32);
        al[i] = *(const bf16x8*)(xl + i * 32);
    }
#pragma unroll
    for (int i = 0; i < NKT; ++i) {
        bh[i] = *(const bf16x8*)(wt + (size_t)i * 2048);
        bl[i] = *(const bf16x8*)(wt + (size_t)i * 2048 + 1024);
    }
    f32x4 a0 = {0.f, 0.f, 0.f, 0.f}, a1 = {0.f, 0.f, 0.f, 0.f};
#pragma unroll
    for (int i = 0; i < NKT; ++i) {
        f32x4& a = (i & 1) ? a1 : a0;
        a = __builtin_amdgcn_mfma_f32_16x16x32_bf16(ah[i], bh[i], a, 0, 0, 0);
        a = __builtin_amdgcn_mfma_f32_16x16x32_bf16(ah[i], bl[i], a, 0, 0, 0);
        a = __builtin_amdgcn_mfma_f32_16x16x32_bf16(al[i], bh[i], a, 0, 0, 0);
    }
    return a0 + a1;
}

template<int NKT>
__device__ __forceinline__ f32x4 xphase_cvt(const float* xp,
                                            const unsigned short* wt) {
    float4 xr[2 * NKT];
#pragma unroll
    for (int i = 0; i < NKT; ++i) {
        xr[2 * i]     = *(const float4*)(xp + i * 32);
        xr[2 * i + 1] = *(const float4*)(xp + i * 32 + 4);
    }
    bf16x8 bh[NKT], bl[NKT];
#pragma unroll
    for (int i = 0; i < NKT; ++i) {
        bh[i] = *(const bf16x8*)(wt + (size_t)i * 2048);
        bl[i] = *(const bf16x8*)(wt + (size_t)i * 2048 + 1024);
    }
    f32x4 a0 = {0.f, 0.f, 0.f, 0.f}, a1 = {0.f, 0.f, 0.f, 0.f};
#pragma unroll
    for (int i = 0; i < NKT; ++i) {
        float f[8] = {xr[2*i].x, xr[2*i].y, xr[2*i].z, xr[2*i].w,
                      xr[2*i+1].x, xr[2*i+1].y, xr[2*i+1].z, xr[2*i+1].w};
        bf16x8 ah, al;
#pragma unroll
        for (int j = 0; j < 8; ++j) {
            unsigned short h16, l16;
            split2(f[j], h16, l16);
            ah[j] = (short)h16; al[j] = (short)l16;
        }
        f32x4& a = (i & 1) ? a1 : a0;
        a = __builtin_amdgcn_mfma_f32_16x16x32_bf16(ah, bh[i], a, 0, 0, 0);
        a = __builtin_amdgcn_mfma_f32_16x16x32_bf16(ah, bl[i], a, 0, 0, 0);
        a = __builtin_amdgcn_mfma_f32_16x16x32_bf16(al, bh[i], a, 0, 0, 0);
    }
    return a0 + a1;
}

template<int NKT>
__device__ __forceinline__ f32x4 hphase(const unsigned short* hh,
                                        const unsigned short* hl,
                                        const unsigned short* wlds, f32x4 acc) {
    bf16x8 ah[NKT], al[NKT], bh[NKT], bl[NKT];
#pragma unroll
    for (int i = 0; i < NKT; ++i) {
        ah[i] = ald16(hh + i * 32);
        al[i] = ald16(hl + i * 32);
    }
#pragma unroll
    for (int i = 0; i < NKT; ++i) {
        bh[i] = *(const bf16x8*)(wlds + (size_t)i * 2048);
        bl[i] = *(const bf16x8*)(wlds + (size_t)i * 2048 + 1024);
    }
    f32x4 a0 = acc, a1 = {0.f, 0.f, 0.f, 0.f};
#pragma unroll
    for (int i = 0; i < NKT; ++i) {
        f32x4& a = (i & 1) ? a1 : a0;
        a = __builtin_amdgcn_mfma_f32_16x16x32_bf16(ah[i], bh[i], a, 0, 0, 0);
        a = __builtin_amdgcn_mfma_f32_16x16x32_bf16(ah[i], bl[i], a, 0, 0, 0);
        a = __builtin_amdgcn_mfma_f32_16x16x32_bf16(al[i], bh[i], a, 0, 0, 0);
    }
    return a0 + a1;
}

// ---------------------------------------------------------------------------
// Persistent kernel: 200 blocks (u, mhalf) x 512 threads (8 waves).
// Wave w: nt=w&1, mt=(w>>1)&1, kh=w>>2 (K halves 13/12 kt).
// Per step: hphase -> epilogue -> sync -> arrive(flag) -> xphase(t+1)
//           [overlapped with others' arrivals] -> parallel poll -> sync.
// ---------------------------------------------------------------------------
__global__ __launch_bounds__(512, 2) void lstm_persist(
        const float* __restrict__ x,
        const unsigned short* __restrict__ wbuf,
        const float* __restrict__ biasbuf,
        unsigned short* __restrict__ hhi,   // [2][64][800]
        unsigned short* __restrict__ hlo,
        float* __restrict__ cbuf,
        float* __restrict__ out,
        unsigned int* __restrict__ flags,   // [NBLK]
        const unsigned short* __restrict__ xhi,
        const unsigned short* __restrict__ xlo,
        int use_pre) {
    extern __shared__ unsigned short whh[];   // 25 kt * 2048 shorts = 102400 B
    __shared__ float gl[2][32][33];

    int bid = blockIdx.x;
    int u = bid >> 1, mhalf = bid & 1;
    int tid = threadIdx.x;
    int lane = tid & 63;
    int w = tid >> 6;
    int nt = w & 1, mt = (w >> 1) & 1, kh = w >> 2;
    int rlane = lane & 15, ksel = lane >> 4, kgrp = ksel * 8;
    int brow = mhalf * 32 + mt * 16 + rlane;

    // ---- stage this u's W_hh tiles (kt 25..49) into LDS ----
    {
        const uint4* src = (const uint4*)(wbuf + ((size_t)u * KT_TOT + KT_X) * 2048);
        uint4* dst = (uint4*)whh;
        for (int g = tid; g < 6400; g += 512) dst[g] = src[g];
    }
    __syncthreads();

    const unsigned short* wih_tile =
        wbuf + (size_t)u * KT_TOT * 2048 + (nt * 16 + rlane) * 32 + kgrp;
    const unsigned short* whh_tile = whh + (nt * 16 + rlane) * 32 + kgrp;

    // epilogue constants (tid<256 -> 32 batch-rows x 8 units)
    int bl_ = tid >> 3, jl = tid & 7;
    int b  = mhalf * 32 + bl_;
    int ju = u * 8 + jl;
    size_t sidx = (size_t)b * H_SZ + ju;
    float b_i = 0.f, b_f = 0.f, b_g = 0.f, b_o = 0.f;
    if (tid < 256) {
        b_i = biasbuf[u * 32 + jl];
        b_f = biasbuf[u * 32 + 8 + jl];
        b_g = biasbuf[u * 32 + 16 + jl];
        b_o = biasbuf[u * 32 + 24 + jl];
    }

    // x contribution for a given timestep (wave's K-half)
    auto do_xphase = [&](int tt) -> f32x4 {
        if (use_pre) {
            const unsigned short* xh = xhi + ((size_t)tt * B_SZ + brow) * H_SZ + kgrp;
            const unsigned short* xl = xlo + ((size_t)tt * B_SZ + brow) * H_SZ + kgrp;
            return (kh == 0) ? xphase_pre<13>(xh, xl, wih_tile)
                             : xphase_pre<12>(xh + 13 * 32, xl + 13 * 32,
                                              wih_tile + 13 * 2048);
        } else {
            const float* xrow = x + ((size_t)tt * B_SZ + brow) * H_SZ + kgrp;
            return (kh == 0) ? xphase_cvt<13>(xrow, wih_tile)
                             : xphase_cvt<12>(xrow + 13 * 32, wih_tile + 13 * 2048);
        }
    };

    f32x4 xacc = do_xphase(0);

    for (int t = 0; t < T_STEPS; ++t) {
        // ---- h phase: A = h_{t-1} via coherent atomic loads, B from LDS.
        //      (t=0 reads the zeroed buffer; barrier at end of t-1 ensured
        //       h_{t-1} visibility for t>0.) ----
        {
            int pprev = (t + 1) & 1;
            const unsigned short* hh =
                hhi + (size_t)pprev * 51200 + (size_t)brow * H_SZ + kgrp;
            const unsigned short* hl =
                hlo + (size_t)pprev * 51200 + (size_t)brow * H_SZ + kgrp;
            xacc = (kh == 0)
                ? hphase<13>(hh, hl, whh_tile, xacc)
                : hphase<12>(hh + 13 * 32, hl + 13 * 32,
                             whh_tile + 13 * 2048, xacc);
        }

        // ---- gate exchange + epilogue ----
#pragma unroll
        for (int j = 0; j < 4; ++j)
            gl[kh][mt * 16 + ksel * 4 + j][nt * 16 + rlane] = xacc[j];
        __syncthreads();
        if (tid < 256) {
            float gi = gl[0][bl_][jl]      + gl[1][bl_][jl]      + b_i;
            float gf = gl[0][bl_][8 + jl]  + gl[1][bl_][8 + jl]  + b_f;
            float gg = gl[0][bl_][16 + jl] + gl[1][bl_][16 + jl] + b_g;
            float go = gl[0][bl_][24 + jl] + gl[1][bl_][24 + jl] + b_o;
            float cold = cbuf[sidx];
            float ig = sigmoid_fast(gi);
            float fg = sigmoid_fast(gf);
            float gt = tanh_fast(gg);
            float og = sigmoid_fast(go);
            float cn = fg * cold + ig * gt;
            float hn = og * tanh_fast(cn);
            cbuf[sidx] = cn;
            __builtin_nontemporal_store(hn, out + ((size_t)t * B_SZ + b) * H_SZ + ju);
            unsigned short h16, l16;
            split2(hn, h16, l16);
            size_t pcur = (size_t)(t & 1) * 51200;
            __hip_atomic_store(hhi + pcur + sidx, h16,
                               __ATOMIC_RELAXED, __HIP_MEMORY_SCOPE_AGENT);
            __hip_atomic_store(hlo + pcur + sidx, l16,
                               __ATOMIC_RELAXED, __HIP_MEMORY_SCOPE_AGENT);
        }

        // ---- drain h stores (syncthreads = vmcnt(0) for every wave), then
        //      arrive: one uncontended flag store per block ----
        __syncthreads();
        if (tid == 0)
            __hip_atomic_store(flags + bid, (unsigned)(t + 1),
                               __ATOMIC_RELAXED, __HIP_MEMORY_SCOPE_AGENT);

        // ---- overlap: next step's x contribution while others arrive ----
        if (t + 1 < T_STEPS)
            xacc = do_xphase(t + 1);

        // ---- parallel poll: 200 threads each watch one flag ----
        if (tid < NBLK) {
            while (__hip_atomic_load(flags + tid, __ATOMIC_RELAXED,
                                     __HIP_MEMORY_SCOPE_AGENT) < (unsigned)(t + 1))
                __builtin_amdgcn_s_sleep(1);
        }
        __syncthreads();
        // h_t from all blocks now visible (flag stored after producer's
        // vmcnt-drain; both flag and h served by the L3 coherence point).
    }
}

// ---------------------------------------------------------------------------
extern "C" void kernel_launch(void* const* d_in, const int* in_sizes, int n_in,
                              void* d_out, int out_size, void* d_ws, size_t ws_size,
                              hipStream_t stream) {
    const float* x   = (const float*)d_in[0];
    const float* Wih = (const float*)d_in[1];
    const float* Whh = (const float*)d_in[2];
    const float* bih = (const float*)d_in[3];
    const float* bhh = (const float*)d_in[4];
    float* out = (float*)d_out;

    char* ws = (char*)d_ws;
    float* cbuf          = (float*)(ws + OFF_C);
    unsigned short* hhi  = (unsigned short*)(ws + OFF_HHI);
    unsigned short* hlo  = (unsigned short*)(ws + OFF_HLO);
    unsigned int* flags  = (unsigned int*)(ws + OFF_FLAGS);
    float* biasbuf       = (float*)(ws + OFF_BIAS);
    unsigned short* wbuf = (unsigned short*)(ws + OFF_WBUF);
    unsigned short* xhi  = (unsigned short*)(ws + OFF_XHI);
    unsigned short* xlo  = (unsigned short*)(ws + OFF_XLO);
    int use_pre = (ws_size >= WS_NEED_PRE) ? 1 : 0;

    // zero c, h[2] (hi/lo), flags (ws is re-poisoned before each call)
    hipMemsetAsync(ws, 0, OFF_BIAS, stream);

    lstm_prep<<<NU * KT_TOT, 256, 0, stream>>>(Wih, Whh, bih, bhh, wbuf, biasbuf);
    if (use_pre)
        lstm_xsplit<<<25600, 256, 0, stream>>>(x, xhi, xlo);

    hipFuncSetAttribute((const void*)lstm_persist,
                        hipFuncAttributeMaxDynamicSharedMemorySize, 102400);
    void* args[] = {(void*)&x, (void*)&wbuf, (void*)&biasbuf, (void*)&hhi,
                    (void*)&hlo, (void*)&cbuf, (void*)&out, (void*)&flags,
                    (void*)&xhi, (void*)&xlo, (void*)&use_pre};
    hipLaunchCooperativeKernel((const void*)lstm_persist, dim3(NBLK), dim3(512),
                               args, 102400, stream);
}